// Round 18
// baseline (41.349 us; speedup 1.0000x reference)
//
#include <hip/hip_runtime.h>

// Problem constants
#define NSPLIT  100
#define MTREE   20
#define MAXLEAF 64
#define EMB     32
#define NTREES  2000
#define BATCH   4096
#define OUTW    (NSPLIT*EMB)             // 3200
#define TAB_F4  (NSPLIT*MTREE*MAXLEAF*8) // 1,024,000 float4 in f32 table

#define ROWSTRIDE 80                     // 64B bf16 row + 16B pad
#define SPLIT_PB  (MTREE*MAXLEAF*ROWSTRIDE)   // 102400 padded bytes / split
#define THREADS 1024
#define CHUNKS  8
#define BPC     (BATCH/CHUNKS)           // 512 batches/block, 2 per group
#define NBLK    (NSPLIT*CHUNKS)          // 800

// v18 = v15 with ONE change under test: 80B row stride (bank spreading).
//  - Row r base bank = (20r)%32 -> cycles 8 quad-bank classes (64B stride
//    confines rows to 2 half-bank windows -> ~8-way per-bank pileups; the
//    conflict counter 2.149M has been byte-identical across v6-v16 = fixed
//    function of the leaves at 64B stride).
//  - The PAD LIVES IN d_ws: cvt writes row r at r*80 (holes never read,
//    stay poison -- never consumed). DMA stages the padded image LINEARLY:
//    writes conflict-free, LDS image == d_ws image (rule-21 both-sides).
//    v17's mistake: produced the padded layout via 4-way-conflicted
//    ds_writes + 131MB f32 reg-staging.
//  - Cost accepted for the A/B: 100 KiB LDS -> 1 block/CU (16 waves).
//    Outstanding-reads arithmetic: 16 waves x 2-3 deep >> ~10 needed to
//    saturate the port. If dur >= 37us, wave count was binding instead.
__device__ __forceinline__ unsigned int pk_bf16(float a, float b) {
    unsigned int r;
    asm("v_cvt_pk_bf16_f32 %0, %1, %2" : "=v"(r) : "v"(a), "v"(b));
    return r;
}

__device__ __forceinline__ void stage_dma(const void* gsrc, void* lbase) {
    __builtin_amdgcn_global_load_lds(
        (const __attribute__((address_space(1))) void*)gsrc,
        (__attribute__((address_space(3))) void*)lbase, 16, 0, 0);
}

// a += 1.0 * (selected bf16 half of w): one VOP3P dot2.
__device__ __forceinline__ void d2(float& a, unsigned int w, unsigned int sel) {
    asm("v_dot2_f32_bf16 %0, %1, %2, %0" : "+v"(a) : "v"(w), "v"(sel));
}

// ---- kernel 1: f32 table -> PADDED bf16 table in d_ws (row r at r*80) ----
__global__ __launch_bounds__(256) void cvt_tab(
    const float4* __restrict__ src, char* __restrict__ dst)
{
    const int i0 = blockIdx.x * 1024 + threadIdx.x;
#pragma unroll
    for (int k = 0; k < 4; ++k) {
        const int i = i0 + k * 256;          // 1000 blocks x 1024 = exact
        const float4 v = src[i];
        const int row = i >> 3;              // 8 float4 per 32-dim row
        const int h   = i & 7;
        *(uint2*)(dst + (size_t)row * ROWSTRIDE + h * 8) =
            make_uint2(pk_bf16(v.x, v.y), pk_bf16(v.z, v.w));
    }
}

// ---- kernel 2: whole padded table in LDS, dot2 gather ----
__global__ __launch_bounds__(THREADS, 1) void leaf2emb_v18(
    const int* __restrict__ leaves,     // [BATCH, NTREES]
    const char* __restrict__ tab,       // padded bf16 table in d_ws
    float* __restrict__ out)            // [BATCH, OUTW]
{
    __shared__ char tl[SPLIT_PB];       // 100 KiB

    // XCD-chunked swizzle: 800 = 8 x 100.
    const int bid = blockIdx.x;
    const int wkr = (bid & 7) * (NBLK / 8) + (bid >> 3);
    const int s     = wkr >> 3;
    const int chunk = wkr & 7;

    const int tid  = threadIdx.x;
    const int l    = tid & 3;           // lane-in-group: dims [8l, 8l+8)
    const int g    = tid >> 2;          // group id (256 groups, 2 batches each)
    const int w    = tid >> 6;          // wave id
    const int lane = tid & 63;

    // stage padded image linearly: 100 x 1KB chunks over 16 waves (6-7 each)
    {
        const char* gs = tab + (size_t)s * SPLIT_PB + lane * 16;
        for (int c = w; c < 100; c += 16)
            stage_dma(gs + c * 1024, tl + c * 1024);
    }

    const int bA = chunk * BPC + g;
    const int bB = bA + 256;
    const int4* lvA = (const int4*)(leaves + (size_t)bA * NTREES + s * MTREE);
    const int4* lvB = (const int4*)(leaves + (size_t)bB * NTREES + s * MTREE);

    // both batches' leaves in flight during the staging drain
    int4 L0 = lvA[0], L1 = lvA[1], L2 = lvA[2], L3 = lvA[3], L4 = lvA[4];
    int4 M0 = lvB[0], M1 = lvB[1], M2 = lvB[2], M3 = lvB[3], M4 = lvB[4];

    __syncthreads();                    // the kernel's ONLY barrier

    // tree t base = t*64*80 = t*5120; two windows keep ds imm <= 65535:
    // trees 0..11 off tb (max 61408), trees 12..19 off tbH (max 40928).
    const char* tb  = tl + l * 16;
    const char* tbH = tb + 12 * 5120;

    const unsigned int selL = 0x00003F80u;   // {hi=0, lo=1.0bf16}
    const unsigned int selH = 0x3F800000u;   // {hi=1.0bf16, lo=0}

#define ROW(BASE, TT, LEAF) \
    (*(const uint4*)((BASE) + (TT) * 5120 + (LEAF) * ROWSTRIDE))
#define D2ACC(V) { \
        d2(a0.x, (V).x, selL); d2(a0.y, (V).x, selH); \
        d2(a0.z, (V).y, selL); d2(a0.w, (V).y, selH); \
        d2(a1.x, (V).z, selL); d2(a1.y, (V).z, selH); \
        d2(a1.z, (V).w, selL); d2(a1.w, (V).w, selH); }
#define QUART(BASE, T0, LQ) { \
        uint4 v0 = ROW(BASE, (T0)+0, (LQ).x), v1 = ROW(BASE, (T0)+1, (LQ).y), \
              v2 = ROW(BASE, (T0)+2, (LQ).z), v3 = ROW(BASE, (T0)+3, (LQ).w); \
        D2ACC(v0) D2ACC(v1) D2ACC(v2) D2ACC(v3) }
#define GATHER20(P0, P1, P2, P3, P4) \
        QUART(tb,  0, P0) QUART(tb,  4, P1) QUART(tb,  8, P2) \
        QUART(tbH, 0, P3) QUART(tbH, 4, P4)

    // ---- batch A ----
    float4 a0 = {0,0,0,0}, a1 = {0,0,0,0};
    GATHER20(L0, L1, L2, L3, L4)
    {
        float* oA = out + (size_t)bA * OUTW + s * EMB + l * 8;
        *(float4*)(oA)     = a0;
        *(float4*)(oA + 4) = a1;
    }

    // ---- batch B ----
    a0 = make_float4(0, 0, 0, 0);
    a1 = make_float4(0, 0, 0, 0);
    GATHER20(M0, M1, M2, M3, M4)
    {
        float* oB = out + (size_t)bB * OUTW + s * EMB + l * 8;
        *(float4*)(oB)     = a0;
        *(float4*)(oB + 4) = a1;
    }

#undef ROW
#undef D2ACC
#undef QUART
#undef GATHER20
}

extern "C" void kernel_launch(void* const* d_in, const int* in_sizes, int n_in,
                              void* d_out, int out_size, void* d_ws, size_t ws_size,
                              hipStream_t stream) {
    const int* leaves  = (const int*)d_in[0];
    const float* embed = (const float*)d_in[1];
    float* out         = (float*)d_out;

    // d_ws: 10.24 MB padded bf16 table (all read rows rewritten every call).
    cvt_tab<<<dim3(TAB_F4 / 1024), dim3(256), 0, stream>>>(
        (const float4*)embed, (char*)d_ws);

    leaf2emb_v18<<<dim3(NBLK), dim3(THREADS), 0, stream>>>(
        leaves, (const char*)d_ws, out);
}

// Round 19
// 34.161 us; speedup vs baseline: 1.2104x; 1.2104x over previous
//
#include <hip/hip_runtime.h>

// Problem constants
#define NSPLIT  100
#define MTREE   20
#define MAXLEAF 64
#define EMB     32
#define NTREES  2000
#define BATCH   4096
#define OUTW    (NSPLIT*EMB)             // 3200
#define TAB_F4  (NSPLIT*MTREE*MAXLEAF*8) // 1,024,000 float4 in f32 table
#define SPLIT_B 81920                    // bf16 table bytes per split

#define THREADS 1024
#define CHUNKS  8                        // batch-chunks per split
#define BPC     (BATCH/CHUNKS)           // 512 batches/block, 2 per group
#define NBLK    (NSPLIT*CHUNKS)          // 800

// v19 = v15 (the 36.0us champion) with its provably-dead intra-row swizzle
// stripped (conflict counter was byte-identical with/without it; it only
// cost VALU on every gather address and complicated cvt).
// Final structure, each piece the measured winner of an A/B:
//  - one-time f32->bf16 cvt into d_ws (fused variants: +4.7us, v17);
//  - whole 80 KiB split table in static LDS via linear global_load_lds DMA
//    (reg-staging: +12us v17; 40 KiB 2-pass: +4us v12; f32 160 KiB: +5us v4);
//  - 2 blocks/CU co-resident, 32 waves (100 KiB/1 block: +5us, v18);
//  - dot2 bf16 accumulate (shift/and/add unpack: +3.7us, v14);
//  - compiler-scheduled gather chains (forced ISA pipeline: +5.7us, v16);
//  - one barrier, 800 blocks, XCD-chunked swizzle.
// Falsified along the way: bank-spreading (v18: conflicts UP at 80B stride),
// source-level ILP depth (v15: allocator flattens to VGPR 40), staging-
// traffic dominance (v14: 65 MB == 262 MB wall), global-path offload (v5).
__device__ __forceinline__ unsigned int pk_bf16(float a, float b) {
    unsigned int r;
    asm("v_cvt_pk_bf16_f32 %0, %1, %2" : "=v"(r) : "v"(a), "v"(b));
    return r;
}

__device__ __forceinline__ void stage_dma(const void* gsrc, void* lbase) {
    __builtin_amdgcn_global_load_lds(
        (const __attribute__((address_space(1))) void*)gsrc,
        (__attribute__((address_space(3))) void*)lbase, 16, 0, 0);
}

// a += 1.0 * (selected bf16 half of w): one VOP3P dot2.
__device__ __forceinline__ void d2(float& a, unsigned int w, unsigned int sel) {
    asm("v_dot2_f32_bf16 %0, %1, %2, %0" : "+v"(a) : "v"(w), "v"(sel));
}

// ---- kernel 1: f32 table -> bf16 table in d_ws (row-major, linear) ----
__global__ __launch_bounds__(256) void cvt_tab(
    const float4* __restrict__ src, uint2* __restrict__ dst)
{
    const int i0 = blockIdx.x * 1024 + threadIdx.x;
#pragma unroll
    for (int k = 0; k < 4; ++k) {
        const int i = i0 + k * 256;          // 1000 blocks x 1024 = exact
        const float4 v = src[i];
        dst[i] = make_uint2(pk_bf16(v.x, v.y), pk_bf16(v.z, v.w));
    }
}

// ---- kernel 2: whole-table LDS gather, dot2 accumulate ----
__global__ __launch_bounds__(THREADS, 1) void leaf2emb_v19(
    const int* __restrict__ leaves,     // [BATCH, NTREES]
    const char* __restrict__ tab,       // bf16 table in d_ws, row = 64 B
    float* __restrict__ out)            // [BATCH, OUTW]
{
    __shared__ char tl[SPLIT_B];        // 80 KiB: whole split table

    // XCD-chunked swizzle: 800 = 8 x 100.
    const int bid = blockIdx.x;
    const int wkr = (bid & 7) * (NBLK / 8) + (bid >> 3);
    const int s     = wkr >> 3;
    const int chunk = wkr & 7;

    const int tid  = threadIdx.x;
    const int l    = tid & 3;           // lane-in-group: dims [8l, 8l+8)
    const int g    = tid >> 2;          // group id (256 groups, 2 batches each)
    const int w    = tid >> 6;          // wave id
    const int lane = tid & 63;

    const char* gtab = tab + (size_t)s * SPLIT_B;
    {   // stage whole table linearly: 16 waves x 1KB x 5 rounds = 80 KB
        const char* gs = gtab + w * 1024 + lane * 16;
        char* lb = tl + w * 1024;
#pragma unroll
        for (int k = 0; k < 5; ++k)
            stage_dma(gs + k * 16384, lb + k * 16384);
    }

    const int bA = chunk * BPC + g;
    const int bB = bA + 256;
    const int4* lvA = (const int4*)(leaves + (size_t)bA * NTREES + s * MTREE);
    const int4* lvB = (const int4*)(leaves + (size_t)bB * NTREES + s * MTREE);

    int4 L0 = lvA[0], L1 = lvA[1], L2 = lvA[2], L3 = lvA[3], L4 = lvA[4];

    __syncthreads();                    // the kernel's ONLY barrier

    const char* tb  = tl + l * 16;
    const char* tbH = tb + 65536;       // trees 16..19 window (ds imm < 64K)

    const unsigned int selL = 0x00003F80u;   // {hi=0, lo=1.0bf16}
    const unsigned int selH = 0x3F800000u;   // {hi=1.0bf16, lo=0}

#define ROWL(T, LEAF) (*(const uint4*)(tb  + (T) * 4096 + ((LEAF) << 6)))
#define ROWH(T, LEAF) (*(const uint4*)(tbH + ((T) - 16) * 4096 + ((LEAF) << 6)))
#define D2ACC(V) { \
        d2(a0.x, (V).x, selL); d2(a0.y, (V).x, selH); \
        d2(a0.z, (V).y, selL); d2(a0.w, (V).y, selH); \
        d2(a1.x, (V).z, selL); d2(a1.y, (V).z, selH); \
        d2(a1.z, (V).w, selL); d2(a1.w, (V).w, selH); }

    float4 a0 = {0,0,0,0}, a1 = {0,0,0,0};

    // ---- batch A: 16 reads issued up front, B-leaves load under consume ----
    uint4 v00 = ROWL(0,  L0.x), v01 = ROWL(1,  L0.y), v02 = ROWL(2,  L0.z), v03 = ROWL(3,  L0.w);
    uint4 v04 = ROWL(4,  L1.x), v05 = ROWL(5,  L1.y), v06 = ROWL(6,  L1.z), v07 = ROWL(7,  L1.w);
    uint4 v08 = ROWL(8,  L2.x), v09 = ROWL(9,  L2.y), v10 = ROWL(10, L2.z), v11 = ROWL(11, L2.w);
    uint4 v12 = ROWL(12, L3.x), v13 = ROWL(13, L3.y), v14 = ROWL(14, L3.z), v15 = ROWL(15, L3.w);
    uint4 v16 = ROWH(16, L4.x), v17 = ROWH(17, L4.y), v18 = ROWH(18, L4.z), v19 = ROWH(19, L4.w);
    int4 M0 = lvB[0], M1 = lvB[1], M2 = lvB[2], M3 = lvB[3], M4 = lvB[4];
    D2ACC(v00) D2ACC(v01) D2ACC(v02) D2ACC(v03)
    D2ACC(v04) D2ACC(v05) D2ACC(v06) D2ACC(v07)
    D2ACC(v08) D2ACC(v09) D2ACC(v10) D2ACC(v11)
    D2ACC(v12) D2ACC(v13) D2ACC(v14) D2ACC(v15)
    D2ACC(v16) D2ACC(v17) D2ACC(v18) D2ACC(v19)
    {
        float* oA = out + (size_t)bA * OUTW + s * EMB + l * 8;
        *(float4*)(oA)     = a0;
        *(float4*)(oA + 4) = a1;
    }

    // ---- batch B ----
    a0 = make_float4(0, 0, 0, 0);
    a1 = make_float4(0, 0, 0, 0);
    v00 = ROWL(0,  M0.x); v01 = ROWL(1,  M0.y); v02 = ROWL(2,  M0.z); v03 = ROWL(3,  M0.w);
    v04 = ROWL(4,  M1.x); v05 = ROWL(5,  M1.y); v06 = ROWL(6,  M1.z); v07 = ROWL(7,  M1.w);
    v08 = ROWL(8,  M2.x); v09 = ROWL(9,  M2.y); v10 = ROWL(10, M2.z); v11 = ROWL(11, M2.w);
    v12 = ROWL(12, M3.x); v13 = ROWL(13, M3.y); v14 = ROWL(14, M3.z); v15 = ROWL(15, M3.w);
    v16 = ROWH(16, M4.x); v17 = ROWH(17, M4.y); v18 = ROWH(18, M4.z); v19 = ROWH(19, M4.w);
    D2ACC(v00) D2ACC(v01) D2ACC(v02) D2ACC(v03)
    D2ACC(v04) D2ACC(v05) D2ACC(v06) D2ACC(v07)
    D2ACC(v08) D2ACC(v09) D2ACC(v10) D2ACC(v11)
    D2ACC(v12) D2ACC(v13) D2ACC(v14) D2ACC(v15)
    D2ACC(v16) D2ACC(v17) D2ACC(v18) D2ACC(v19)
    {
        float* oB = out + (size_t)bB * OUTW + s * EMB + l * 8;
        *(float4*)(oB)     = a0;
        *(float4*)(oB + 4) = a1;
    }

#undef ROWL
#undef ROWH
#undef D2ACC
}

extern "C" void kernel_launch(void* const* d_in, const int* in_sizes, int n_in,
                              void* d_out, int out_size, void* d_ws, size_t ws_size,
                              hipStream_t stream) {
    const int* leaves  = (const int*)d_in[0];
    const float* embed = (const float*)d_in[1];
    float* out         = (float*)d_out;

    // d_ws: 8.2 MB bf16 table (fully rewritten every call -> deterministic).
    cvt_tab<<<dim3(TAB_F4 / 1024), dim3(256), 0, stream>>>(
        (const float4*)embed, (uint2*)d_ws);

    leaf2emb_v19<<<dim3(NBLK), dim3(THREADS), 0, stream>>>(
        leaves, (const char*)d_ws, out);
}

// Round 20
// 29.897 us; speedup vs baseline: 1.3830x; 1.1426x over previous
//
#include <hip/hip_runtime.h>

// Problem constants
#define NSPLIT  100
#define MTREE   20
#define MAXLEAF 64
#define EMB     32
#define NTREES  2000
#define BATCH   4096
#define OUTW    (NSPLIT*EMB)            // 3200
#define SPLIT_B 81920                   // bf16 table bytes per split

#define THREADS 1024
#define CHUNKS  8                       // batch-chunks per split
#define BPC     (BATCH/CHUNKS)          // 512 batches/block, 2 per group
#define NBLK    (NSPLIT*CHUNKS)         // 800

// v20 = v19 (34.2us champion) with the separate cvt kernel DELETED.
// The cvt dispatch was ~4-5us of strictly-serial time (25 MB HBM + launch,
// stream-ordered before the gather). Fused staging here avoids v17's three
// bundled defects: 64B stride (linear ds_write_b64, conflict-free -- v17's
// 80B-stride writes added +0.7M conflict cycles), 80 KiB LDS (2 blocks/CU;
// v17's 100 KiB forced 1/CU = +5us per v18), layout unchanged for the reads.
// Cost accepted: f32 table read 8x-redundant (131 MB aggregate) -- each
// XCD's slice is 2 MB, L2-resident, ~4us of OVERLAPPABLE L2 time vs 4-5us
// of serial cvt time removed; 20 cvt_pk/thread hides under 32-wave TLP.
// Gather body byte-identical to v19 (dot2, one barrier, 16-deep quartets).
__device__ __forceinline__ unsigned int pk_bf16(float a, float b) {
    unsigned int r;
    asm("v_cvt_pk_bf16_f32 %0, %1, %2" : "=v"(r) : "v"(a), "v"(b));
    return r;
}

// a += 1.0 * (selected bf16 half of w): one VOP3P dot2.
__device__ __forceinline__ void d2(float& a, unsigned int w, unsigned int sel) {
    asm("v_dot2_f32_bf16 %0, %1, %2, %0" : "+v"(a) : "v"(w), "v"(sel));
}

__global__ __launch_bounds__(THREADS, 1) void leaf2emb_v20(
    const int* __restrict__ leaves,     // [BATCH, NTREES]
    const float* __restrict__ embed,    // [NSPLIT, MTREE*MAXLEAF, EMB] f32
    float* __restrict__ out)            // [BATCH, OUTW]
{
    __shared__ char tl[SPLIT_B];        // 80 KiB: whole split table, bf16

    // XCD-chunked swizzle: 800 = 8 x 100 -> a split's 8 blocks share an XCD;
    // its 2 MB f32 slice stays L2-resident across the 8 re-reads.
    const int bid = blockIdx.x;
    const int wkr = (bid & 7) * (NBLK / 8) + (bid >> 3);
    const int s     = wkr >> 3;
    const int chunk = wkr & 7;

    const int tid = threadIdx.x;
    const int l   = tid & 3;            // lane-in-group: dims [8l, 8l+8)
    const int g   = tid >> 2;           // group id (256 groups, 2 batches each)

    // ---- fused staging: f32 global -> cvt_pk -> LINEAR bf16 LDS ----
    // i = tid + k*1024 covers 10240 float4; each float4 -> 8 B at byte i*8.
    // Dense linear ds_write_b64: conflict-free bank sweep.
    {
        const float4* emb4 = (const float4*)embed + (size_t)s * 10240;
#pragma unroll 2
        for (int k = 0; k < 10; ++k) {
            const int i = tid + k * 1024;
            const float4 v = emb4[i];
            *(uint2*)(tl + i * 8) =
                make_uint2(pk_bf16(v.x, v.y), pk_bf16(v.z, v.w));
        }
    }

    const int bA = chunk * BPC + g;
    const int bB = bA + 256;
    const int4* lvA = (const int4*)(leaves + (size_t)bA * NTREES + s * MTREE);
    const int4* lvB = (const int4*)(leaves + (size_t)bB * NTREES + s * MTREE);

    // batch-A leaves in flight during the staging tail
    int4 L0 = lvA[0], L1 = lvA[1], L2 = lvA[2], L3 = lvA[3], L4 = lvA[4];

    __syncthreads();                    // the kernel's ONLY barrier

    const char* tb  = tl + l * 16;
    const char* tbH = tb + 65536;       // trees 16..19 window (ds imm < 64K)

    const unsigned int selL = 0x00003F80u;   // {hi=0, lo=1.0bf16}
    const unsigned int selH = 0x3F800000u;   // {hi=1.0bf16, lo=0}

#define ROWL(T, LEAF) (*(const uint4*)(tb  + (T) * 4096 + ((LEAF) << 6)))
#define ROWH(T, LEAF) (*(const uint4*)(tbH + ((T) - 16) * 4096 + ((LEAF) << 6)))
#define D2ACC(V) { \
        d2(a0.x, (V).x, selL); d2(a0.y, (V).x, selH); \
        d2(a0.z, (V).y, selL); d2(a0.w, (V).y, selH); \
        d2(a1.x, (V).z, selL); d2(a1.y, (V).z, selH); \
        d2(a1.z, (V).w, selL); d2(a1.w, (V).w, selH); }

    float4 a0 = {0,0,0,0}, a1 = {0,0,0,0};

    // ---- batch A: 16 reads issued up front, B-leaves load under consume ----
    uint4 v00 = ROWL(0,  L0.x), v01 = ROWL(1,  L0.y), v02 = ROWL(2,  L0.z), v03 = ROWL(3,  L0.w);
    uint4 v04 = ROWL(4,  L1.x), v05 = ROWL(5,  L1.y), v06 = ROWL(6,  L1.z), v07 = ROWL(7,  L1.w);
    uint4 v08 = ROWL(8,  L2.x), v09 = ROWL(9,  L2.y), v10 = ROWL(10, L2.z), v11 = ROWL(11, L2.w);
    uint4 v12 = ROWL(12, L3.x), v13 = ROWL(13, L3.y), v14 = ROWL(14, L3.z), v15 = ROWL(15, L3.w);
    uint4 v16 = ROWH(16, L4.x), v17 = ROWH(17, L4.y), v18 = ROWH(18, L4.z), v19 = ROWH(19, L4.w);
    int4 M0 = lvB[0], M1 = lvB[1], M2 = lvB[2], M3 = lvB[3], M4 = lvB[4];
    D2ACC(v00) D2ACC(v01) D2ACC(v02) D2ACC(v03)
    D2ACC(v04) D2ACC(v05) D2ACC(v06) D2ACC(v07)
    D2ACC(v08) D2ACC(v09) D2ACC(v10) D2ACC(v11)
    D2ACC(v12) D2ACC(v13) D2ACC(v14) D2ACC(v15)
    D2ACC(v16) D2ACC(v17) D2ACC(v18) D2ACC(v19)
    {
        float* oA = out + (size_t)bA * OUTW + s * EMB + l * 8;
        *(float4*)(oA)     = a0;
        *(float4*)(oA + 4) = a1;
    }

    // ---- batch B ----
    a0 = make_float4(0, 0, 0, 0);
    a1 = make_float4(0, 0, 0, 0);
    v00 = ROWL(0,  M0.x); v01 = ROWL(1,  M0.y); v02 = ROWL(2,  M0.z); v03 = ROWL(3,  M0.w);
    v04 = ROWL(4,  M1.x); v05 = ROWL(5,  M1.y); v06 = ROWL(6,  M1.z); v07 = ROWL(7,  M1.w);
    v08 = ROWL(8,  M2.x); v09 = ROWL(9,  M2.y); v10 = ROWL(10, M2.z); v11 = ROWL(11, M2.w);
    v12 = ROWL(12, M3.x); v13 = ROWL(13, M3.y); v14 = ROWL(14, M3.z); v15 = ROWL(15, M3.w);
    v16 = ROWH(16, M4.x); v17 = ROWH(17, M4.y); v18 = ROWH(18, M4.z); v19 = ROWH(19, M4.w);
    D2ACC(v00) D2ACC(v01) D2ACC(v02) D2ACC(v03)
    D2ACC(v04) D2ACC(v05) D2ACC(v06) D2ACC(v07)
    D2ACC(v08) D2ACC(v09) D2ACC(v10) D2ACC(v11)
    D2ACC(v12) D2ACC(v13) D2ACC(v14) D2ACC(v15)
    D2ACC(v16) D2ACC(v17) D2ACC(v18) D2ACC(v19)
    {
        float* oB = out + (size_t)bB * OUTW + s * EMB + l * 8;
        *(float4*)(oB)     = a0;
        *(float4*)(oB + 4) = a1;
    }

#undef ROWL
#undef ROWH
#undef D2ACC
}

extern "C" void kernel_launch(void* const* d_in, const int* in_sizes, int n_in,
                              void* d_out, int out_size, void* d_ws, size_t ws_size,
                              hipStream_t stream) {
    const int* leaves  = (const int*)d_in[0];
    const float* embed = (const float*)d_in[1];
    float* out         = (float*)d_out;

    leaf2emb_v20<<<dim3(NBLK), dim3(THREADS), 0, stream>>>(leaves, embed, out);
}